// Round 1
// baseline (1186.946 us; speedup 1.0000x reference)
//
#include <hip/hip_runtime.h>

#define NN 10000
#define DIN 128
#define DOUT 256
static constexpr float BN_EPS = 1e-5f;

// ---------------------------------------------------------------------------
// Kernel 1: scatter-add  agg[dst] += x[src]  over E edges, 4-dim chunks/thread
// ---------------------------------------------------------------------------
__global__ __launch_bounds__(256) void scatter_add_k(
    const float* __restrict__ x, const int* __restrict__ ei,
    float* __restrict__ agg, int E) {
    const int total = E * 32;               // E * (128/4) chunks
    for (int u = blockIdx.x * 256 + threadIdx.x; u < total;
         u += gridDim.x * 256) {
        const int e = u >> 5;
        const int c = (u & 31) << 2;        // dim offset 0..124
        const int src = ei[e];
        const int dst = ei[E + e];
        const float4 v =
            *reinterpret_cast<const float4*>(x + (size_t)src * DIN + c);
        float* a = agg + (size_t)dst * DIN + c;
        atomicAdd(a + 0, v.x);
        atomicAdd(a + 1, v.y);
        atomicAdd(a + 2, v.z);
        atomicAdd(a + 3, v.w);
    }
}

// ---------------------------------------------------------------------------
// Kernel 2: h1 = (x + agg) @ W1 + b1, plus per-feature sum/sumsq for BN1
// 8 rows per block, 256 threads = one output column each
// ---------------------------------------------------------------------------
__global__ __launch_bounds__(256) void gemm1_k(
    const float* __restrict__ x, const float* __restrict__ agg,
    const float* __restrict__ W1, const float* __restrict__ b1,
    float* __restrict__ h1, float* __restrict__ sum1, float* __restrict__ sq1) {
    __shared__ float xs[8][DIN];
    const int row0 = blockIdx.x * 8;
    const int tid = threadIdx.x;

    for (int i = tid; i < 8 * DIN; i += 256) {
        const int r = i >> 7, k = i & (DIN - 1);
        const int row = row0 + r;
        float v = 0.f;
        if (row < NN) {
            const size_t o = (size_t)row * DIN + k;
            v = x[o] + agg[o];
        }
        xs[r][k] = v;
    }
    __syncthreads();

    const int j = tid;
    float acc[8];
#pragma unroll
    for (int r = 0; r < 8; ++r) acc[r] = b1[j];
    for (int k = 0; k < DIN; ++k) {
        const float w = W1[(size_t)k * DOUT + j];
#pragma unroll
        for (int r = 0; r < 8; ++r) acc[r] = fmaf(xs[r][k], w, acc[r]);
    }

    float s = 0.f, sq = 0.f;
#pragma unroll
    for (int r = 0; r < 8; ++r) {
        const int row = row0 + r;
        if (row < NN) {
            h1[(size_t)row * DOUT + j] = acc[r];
            s += acc[r];
            sq += acc[r] * acc[r];
        }
    }
    atomicAdd(&sum1[j], s);
    atomicAdd(&sq1[j], sq);
}

// ---------------------------------------------------------------------------
// Kernel 3: BN finalize -> scale/shift per feature
// ---------------------------------------------------------------------------
__global__ void bn_final_k(const float* __restrict__ sum,
                           const float* __restrict__ sq,
                           const float* __restrict__ gamma,
                           const float* __restrict__ beta,
                           float* __restrict__ scale,
                           float* __restrict__ shift) {
    const int j = threadIdx.x;  // 256
    const float nInv = 1.0f / (float)NN;
    const float mean = sum[j] * nInv;
    const float var = sq[j] * nInv - mean * mean;
    const float sc = gamma[j] * rsqrtf(var + BN_EPS);
    scale[j] = sc;
    shift[j] = beta[j] - mean * sc;
}

// ---------------------------------------------------------------------------
// Kernel 4: h2 = relu(bn1(h1)) @ W2 + b2, plus BN2 sums
// ---------------------------------------------------------------------------
__global__ __launch_bounds__(256) void gemm2_k(
    const float* __restrict__ h1, const float* __restrict__ scale1,
    const float* __restrict__ shift1, const float* __restrict__ W2,
    const float* __restrict__ b2, float* __restrict__ h2,
    float* __restrict__ sum2, float* __restrict__ sq2) {
    __shared__ float gs[8][DOUT];
    const int row0 = blockIdx.x * 8;
    const int tid = threadIdx.x;

    for (int i = tid; i < 8 * DOUT; i += 256) {
        const int r = i >> 8, k = i & (DOUT - 1);
        const int row = row0 + r;
        float v = 0.f;
        if (row < NN) {
            v = fmaxf(h1[(size_t)row * DOUT + k] * scale1[k] + shift1[k], 0.f);
        }
        gs[r][k] = v;
    }
    __syncthreads();

    const int j = tid;
    float acc[8];
#pragma unroll
    for (int r = 0; r < 8; ++r) acc[r] = b2[j];
    for (int k = 0; k < DOUT; ++k) {
        const float w = W2[(size_t)k * DOUT + j];
#pragma unroll
        for (int r = 0; r < 8; ++r) acc[r] = fmaf(gs[r][k], w, acc[r]);
    }

    float s = 0.f, sq = 0.f;
#pragma unroll
    for (int r = 0; r < 8; ++r) {
        const int row = row0 + r;
        if (row < NN) {
            h2[(size_t)row * DOUT + j] = acc[r];
            s += acc[r];
            sq += acc[r] * acc[r];
        }
    }
    atomicAdd(&sum2[j], s);
    atomicAdd(&sq2[j], sq);
}

// ---------------------------------------------------------------------------
// Kernel 5: out = relu(bn2(h2))
// ---------------------------------------------------------------------------
__global__ __launch_bounds__(256) void bn_relu_out_k(
    const float* __restrict__ h2, const float* __restrict__ scale2,
    const float* __restrict__ shift2, float* __restrict__ out) {
    const int i = blockIdx.x * 256 + threadIdx.x;
    if (i < NN * DOUT) {
        const int j = i & (DOUT - 1);
        out[i] = fmaxf(h2[i] * scale2[j] + shift2[j], 0.f);
    }
}

// ---------------------------------------------------------------------------
extern "C" void kernel_launch(void* const* d_in, const int* in_sizes, int n_in,
                              void* d_out, int out_size, void* d_ws,
                              size_t ws_size, hipStream_t stream) {
    const float* x      = (const float*)d_in[0];
    const int*   ei     = (const int*)d_in[1];
    const float* W1     = (const float*)d_in[2];
    const float* b1     = (const float*)d_in[3];
    const float* gamma1 = (const float*)d_in[4];
    const float* beta1  = (const float*)d_in[5];
    const float* W2     = (const float*)d_in[6];
    const float* b2     = (const float*)d_in[7];
    const float* gamma2 = (const float*)d_in[8];
    const float* beta2  = (const float*)d_in[9];
    const int E = in_sizes[1] / 2;

    // ws layout (floats): [stats 2048][agg N*DIN][h1 N*DOUT][h2 N*DOUT]
    float* stats  = (float*)d_ws;
    float* sum1   = stats + 0;
    float* sq1    = stats + 256;
    float* scale1 = stats + 512;
    float* shift1 = stats + 768;
    float* sum2   = stats + 1024;
    float* sq2    = stats + 1280;
    float* scale2 = stats + 1536;
    float* shift2 = stats + 1792;
    float* agg    = stats + 2048;
    float* h1     = agg + (size_t)NN * DIN;
    float* h2     = h1 + (size_t)NN * DOUT;
    float* out    = (float*)d_out;

    // zero stats + agg (contiguous)
    hipMemsetAsync(d_ws, 0, (2048 + (size_t)NN * DIN) * sizeof(float), stream);

    scatter_add_k<<<2048, 256, 0, stream>>>(x, ei, agg, E);
    gemm1_k<<<(NN + 7) / 8, 256, 0, stream>>>(x, agg, W1, b1, h1, sum1, sq1);
    bn_final_k<<<1, 256, 0, stream>>>(sum1, sq1, gamma1, beta1, scale1, shift1);
    gemm2_k<<<(NN + 7) / 8, 256, 0, stream>>>(h1, scale1, shift1, W2, b2, h2,
                                              sum2, sq2);
    bn_final_k<<<1, 256, 0, stream>>>(sum2, sq2, gamma2, beta2, scale2, shift2);
    bn_relu_out_k<<<(NN * DOUT + 255) / 256, 256, 0, stream>>>(h2, scale2,
                                                               shift2, out);
}

// Round 2
// 223.487 us; speedup vs baseline: 5.3110x; 5.3110x over previous
//
#include <hip/hip_runtime.h>

#define NN 10000
#define DIN 128
#define DOUT 256
static constexpr float BN_EPS = 1e-5f;

// ---------------------------------------------------------------------------
// Kernel H: per-block LDS histogram of in-degrees
// ---------------------------------------------------------------------------
__global__ __launch_bounds__(256) void hist_k(const int* __restrict__ ei,
                                              int* __restrict__ deg, int E) {
    __shared__ int hist[NN];
    const int tid = threadIdx.x;
    for (int i = tid; i < NN; i += 256) hist[i] = 0;
    __syncthreads();
    for (int e = blockIdx.x * 256 + tid; e < E; e += gridDim.x * 256) {
        atomicAdd(&hist[ei[E + e]], 1);
    }
    __syncthreads();
    for (int i = tid; i < NN; i += 256) {
        const int v = hist[i];
        if (v) atomicAdd(&deg[i], v);
    }
}

// ---------------------------------------------------------------------------
// Kernel S: single-block exclusive scan (10000 -> offsets[10001], cursor copy)
// ---------------------------------------------------------------------------
__global__ __launch_bounds__(1024) void scan_k(const int* __restrict__ deg,
                                               int* __restrict__ offsets,
                                               int* __restrict__ cursor) {
    __shared__ int part[1024];
    const int t = threadIdx.x;
    const int base = t * 10;
    int local[10];
    int s = 0;
#pragma unroll
    for (int k = 0; k < 10; ++k) {
        const int i = base + k;
        const int v = (i < NN) ? deg[i] : 0;
        local[k] = s;
        s += v;
    }
    part[t] = s;
    __syncthreads();
    for (int off = 1; off < 1024; off <<= 1) {
        int v = 0;
        if (t >= off) v = part[t - off];
        __syncthreads();
        if (t >= off) part[t] += v;
        __syncthreads();
    }
    const int prefix = (t == 0) ? 0 : part[t - 1];
#pragma unroll
    for (int k = 0; k < 10; ++k) {
        const int i = base + k;
        if (i < NN) {
            const int o = prefix + local[k];
            offsets[i] = o;
            cursor[i] = o;
        }
    }
    if (t == 1023) offsets[NN] = part[1023];
}

// ---------------------------------------------------------------------------
// Kernel F: CSR fill — edge_src[pos] = src, pos from per-dst cursor
// ---------------------------------------------------------------------------
__global__ __launch_bounds__(256) void fill_k(const int* __restrict__ ei,
                                              int* __restrict__ cursor,
                                              int* __restrict__ edge_src,
                                              int E) {
    for (int e = blockIdx.x * 256 + threadIdx.x; e < E;
         e += gridDim.x * 256) {
        const int src = ei[e];
        const int dst = ei[E + e];
        const int pos = atomicAdd(&cursor[dst], 1);
        edge_src[pos] = src;
    }
}

// ---------------------------------------------------------------------------
// Kernel A: gather-aggregate. One wave per node; lane owns cols [2l,2l+1].
// xin = x + sum_{j->i} x[src_j]   (GIN eps = 0)
// ---------------------------------------------------------------------------
__global__ __launch_bounds__(256) void aggregate_k(
    const float* __restrict__ x, const int* __restrict__ offsets,
    const int* __restrict__ edge_src, float* __restrict__ xin) {
    const int node = blockIdx.x * 4 + (threadIdx.x >> 6);
    if (node >= NN) return;
    const int lane = threadIdx.x & 63;
    const int beg = offsets[node];
    const int end = offsets[node + 1];

    float2 acc = make_float2(0.f, 0.f);
    int j = beg;
    // 2-way unroll for ILP on the gather
    for (; j + 1 < end; j += 2) {
        const int s0 = edge_src[j];
        const int s1 = edge_src[j + 1];
        const float2 v0 =
            *reinterpret_cast<const float2*>(x + (size_t)s0 * DIN + 2 * lane);
        const float2 v1 =
            *reinterpret_cast<const float2*>(x + (size_t)s1 * DIN + 2 * lane);
        acc.x += v0.x + v1.x;
        acc.y += v0.y + v1.y;
    }
    if (j < end) {
        const int s0 = edge_src[j];
        const float2 v0 =
            *reinterpret_cast<const float2*>(x + (size_t)s0 * DIN + 2 * lane);
        acc.x += v0.x;
        acc.y += v0.y;
    }
    const float2 xv =
        *reinterpret_cast<const float2*>(x + (size_t)node * DIN + 2 * lane);
    float2 r;
    r.x = xv.x + acc.x;
    r.y = xv.y + acc.y;
    *reinterpret_cast<float2*>(xin + (size_t)node * DIN + 2 * lane) = r;
}

// ---------------------------------------------------------------------------
// Kernel 2: h1 = xin @ W1 + b1, plus per-feature sum/sumsq for BN1
// ---------------------------------------------------------------------------
__global__ __launch_bounds__(256) void gemm1_k(
    const float* __restrict__ xin, const float* __restrict__ W1,
    const float* __restrict__ b1, float* __restrict__ h1,
    float* __restrict__ sum1, float* __restrict__ sq1) {
    __shared__ float xs[8][DIN];
    const int row0 = blockIdx.x * 8;
    const int tid = threadIdx.x;

    for (int i = tid; i < 8 * DIN; i += 256) {
        const int r = i >> 7, k = i & (DIN - 1);
        const int row = row0 + r;
        xs[r][k] = (row < NN) ? xin[(size_t)row * DIN + k] : 0.f;
    }
    __syncthreads();

    const int j = tid;
    float acc[8];
#pragma unroll
    for (int r = 0; r < 8; ++r) acc[r] = b1[j];
    for (int k = 0; k < DIN; ++k) {
        const float w = W1[(size_t)k * DOUT + j];
#pragma unroll
        for (int r = 0; r < 8; ++r) acc[r] = fmaf(xs[r][k], w, acc[r]);
    }

    float s = 0.f, sq = 0.f;
#pragma unroll
    for (int r = 0; r < 8; ++r) {
        const int row = row0 + r;
        if (row < NN) {
            h1[(size_t)row * DOUT + j] = acc[r];
            s += acc[r];
            sq += acc[r] * acc[r];
        }
    }
    atomicAdd(&sum1[j], s);
    atomicAdd(&sq1[j], sq);
}

// ---------------------------------------------------------------------------
// Kernel 3: BN finalize -> per-feature scale/shift
// ---------------------------------------------------------------------------
__global__ void bn_final_k(const float* __restrict__ sum,
                           const float* __restrict__ sq,
                           const float* __restrict__ gamma,
                           const float* __restrict__ beta,
                           float* __restrict__ scale,
                           float* __restrict__ shift) {
    const int j = threadIdx.x;  // 256
    const float nInv = 1.0f / (float)NN;
    const float mean = sum[j] * nInv;
    const float var = sq[j] * nInv - mean * mean;
    const float sc = gamma[j] * rsqrtf(var + BN_EPS);
    scale[j] = sc;
    shift[j] = beta[j] - mean * sc;
}

// ---------------------------------------------------------------------------
// Kernel 4: h2 = relu(bn1(h1)) @ W2 + b2, plus BN2 sums
// ---------------------------------------------------------------------------
__global__ __launch_bounds__(256) void gemm2_k(
    const float* __restrict__ h1, const float* __restrict__ scale1,
    const float* __restrict__ shift1, const float* __restrict__ W2,
    const float* __restrict__ b2, float* __restrict__ h2,
    float* __restrict__ sum2, float* __restrict__ sq2) {
    __shared__ float gs[8][DOUT];
    const int row0 = blockIdx.x * 8;
    const int tid = threadIdx.x;

    for (int i = tid; i < 8 * DOUT; i += 256) {
        const int r = i >> 8, k = i & (DOUT - 1);
        const int row = row0 + r;
        float v = 0.f;
        if (row < NN) {
            v = fmaxf(h1[(size_t)row * DOUT + k] * scale1[k] + shift1[k], 0.f);
        }
        gs[r][k] = v;
    }
    __syncthreads();

    const int j = tid;
    float acc[8];
#pragma unroll
    for (int r = 0; r < 8; ++r) acc[r] = b2[j];
    for (int k = 0; k < DOUT; ++k) {
        const float w = W2[(size_t)k * DOUT + j];
#pragma unroll
        for (int r = 0; r < 8; ++r) acc[r] = fmaf(gs[r][k], w, acc[r]);
    }

    float s = 0.f, sq = 0.f;
#pragma unroll
    for (int r = 0; r < 8; ++r) {
        const int row = row0 + r;
        if (row < NN) {
            h2[(size_t)row * DOUT + j] = acc[r];
            s += acc[r];
            sq += acc[r] * acc[r];
        }
    }
    atomicAdd(&sum2[j], s);
    atomicAdd(&sq2[j], sq);
}

// ---------------------------------------------------------------------------
// Kernel 5: out = relu(bn2(h2))
// ---------------------------------------------------------------------------
__global__ __launch_bounds__(256) void bn_relu_out_k(
    const float* __restrict__ h2, const float* __restrict__ scale2,
    const float* __restrict__ shift2, float* __restrict__ out) {
    const int i = blockIdx.x * 256 + threadIdx.x;
    if (i < NN * DOUT) {
        const int j = i & (DOUT - 1);
        out[i] = fmaxf(h2[i] * scale2[j] + shift2[j], 0.f);
    }
}

// ---------------------------------------------------------------------------
extern "C" void kernel_launch(void* const* d_in, const int* in_sizes, int n_in,
                              void* d_out, int out_size, void* d_ws,
                              size_t ws_size, hipStream_t stream) {
    const float* x      = (const float*)d_in[0];
    const int*   ei     = (const int*)d_in[1];
    const float* W1     = (const float*)d_in[2];
    const float* b1     = (const float*)d_in[3];
    const float* gamma1 = (const float*)d_in[4];
    const float* beta1  = (const float*)d_in[5];
    const float* W2     = (const float*)d_in[6];
    const float* b2     = (const float*)d_in[7];
    const float* gamma2 = (const float*)d_in[8];
    const float* beta2  = (const float*)d_in[9];
    const int E = in_sizes[1] / 2;

    // ws layout (bytes):
    // [stats 8192][deg 40064][offsets 40064][cursor 40064][edge_src 4E]
    // [xin N*DIN*4][h1 N*DOUT*4][h2 N*DOUT*4]
    char* w = (char*)d_ws;
    float* stats   = (float*)w;                       // 2048 floats
    float* sum1    = stats + 0;
    float* sq1     = stats + 256;
    float* scale1  = stats + 512;
    float* shift1  = stats + 768;
    float* sum2    = stats + 1024;
    float* sq2     = stats + 1280;
    float* scale2  = stats + 1536;
    float* shift2  = stats + 1792;
    int* deg       = (int*)(w + 8192);
    int* offsets   = (int*)(w + 8192 + 40064);
    int* cursor    = (int*)(w + 8192 + 2 * 40064);
    int* edge_src  = (int*)(w + 8192 + 3 * 40064);
    float* xin     = (float*)(w + 8192 + 3 * 40064 + (size_t)E * 4);
    float* h1      = xin + (size_t)NN * DIN;
    float* h2      = h1 + (size_t)NN * DOUT;
    float* out     = (float*)d_out;

    // zero stats + deg (contiguous region)
    hipMemsetAsync(d_ws, 0, 8192 + 40064, stream);

    hist_k<<<80, 256, 0, stream>>>(ei, deg, E);
    scan_k<<<1, 1024, 0, stream>>>(deg, offsets, cursor);
    fill_k<<<2048, 256, 0, stream>>>(ei, cursor, edge_src, E);
    aggregate_k<<<(NN + 3) / 4, 256, 0, stream>>>(x, offsets, edge_src, xin);
    gemm1_k<<<(NN + 7) / 8, 256, 0, stream>>>(xin, W1, b1, h1, sum1, sq1);
    bn_final_k<<<1, 256, 0, stream>>>(sum1, sq1, gamma1, beta1, scale1, shift1);
    gemm2_k<<<(NN + 7) / 8, 256, 0, stream>>>(h1, scale1, shift1, W2, b2, h2,
                                              sum2, sq2);
    bn_final_k<<<1, 256, 0, stream>>>(sum2, sq2, gamma2, beta2, scale2, shift2);
    bn_relu_out_k<<<(NN * DOUT + 255) / 256, 256, 0, stream>>>(h2, scale2,
                                                               shift2, out);
}

// Round 3
// 205.367 us; speedup vs baseline: 5.7796x; 1.0882x over previous
//
#include <hip/hip_runtime.h>

#define NN 10000
#define DIN 128
#define DOUT 256
static constexpr float BN_EPS = 1e-5f;

// ---------------------------------------------------------------------------
// Kernel H: per-block LDS histogram of in-degrees
// ---------------------------------------------------------------------------
__global__ __launch_bounds__(256) void hist_k(const int* __restrict__ ei,
                                              int* __restrict__ deg, int E) {
    __shared__ int hist[NN];
    const int tid = threadIdx.x;
    for (int i = tid; i < NN; i += 256) hist[i] = 0;
    __syncthreads();
    for (int e = blockIdx.x * 256 + tid; e < E; e += gridDim.x * 256) {
        atomicAdd(&hist[ei[E + e]], 1);
    }
    __syncthreads();
    for (int i = tid; i < NN; i += 256) {
        const int v = hist[i];
        if (v) atomicAdd(&deg[i], v);
    }
}

// ---------------------------------------------------------------------------
// Kernel S: single-block exclusive scan (10000 -> offsets[10001], cursor copy)
// ---------------------------------------------------------------------------
__global__ __launch_bounds__(1024) void scan_k(const int* __restrict__ deg,
                                               int* __restrict__ offsets,
                                               int* __restrict__ cursor) {
    __shared__ int part[1024];
    const int t = threadIdx.x;
    const int base = t * 10;
    int local[10];
    int s = 0;
#pragma unroll
    for (int k = 0; k < 10; ++k) {
        const int i = base + k;
        const int v = (i < NN) ? deg[i] : 0;
        local[k] = s;
        s += v;
    }
    part[t] = s;
    __syncthreads();
    for (int off = 1; off < 1024; off <<= 1) {
        int v = 0;
        if (t >= off) v = part[t - off];
        __syncthreads();
        if (t >= off) part[t] += v;
        __syncthreads();
    }
    const int prefix = (t == 0) ? 0 : part[t - 1];
#pragma unroll
    for (int k = 0; k < 10; ++k) {
        const int i = base + k;
        if (i < NN) {
            const int o = prefix + local[k];
            offsets[i] = o;
            cursor[i] = o;
        }
    }
    if (t == 1023) offsets[NN] = part[1023];
}

// ---------------------------------------------------------------------------
// Kernel F: CSR fill — edge_src[pos] = src, pos from per-dst cursor
// ---------------------------------------------------------------------------
__global__ __launch_bounds__(256) void fill_k(const int* __restrict__ ei,
                                              int* __restrict__ cursor,
                                              int* __restrict__ edge_src,
                                              int E) {
    for (int e = blockIdx.x * 256 + threadIdx.x; e < E;
         e += gridDim.x * 256) {
        const int src = ei[e];
        const int dst = ei[E + e];
        const int pos = atomicAdd(&cursor[dst], 1);
        edge_src[pos] = src;
    }
}

// ---------------------------------------------------------------------------
// Kernel A: gather-aggregate. One wave per node; lane owns cols [2l,2l+1].
// xin = x + sum_{j->i} x[src_j]   (GIN eps = 0)
// ---------------------------------------------------------------------------
__global__ __launch_bounds__(256) void aggregate_k(
    const float* __restrict__ x, const int* __restrict__ offsets,
    const int* __restrict__ edge_src, float* __restrict__ xin) {
    const int node = blockIdx.x * 4 + (threadIdx.x >> 6);
    if (node >= NN) return;
    const int lane = threadIdx.x & 63;
    const int beg = offsets[node];
    const int end = offsets[node + 1];

    float2 acc = make_float2(0.f, 0.f);
    int j = beg;
    for (; j + 1 < end; j += 2) {
        const int s0 = edge_src[j];
        const int s1 = edge_src[j + 1];
        const float2 v0 =
            *reinterpret_cast<const float2*>(x + (size_t)s0 * DIN + 2 * lane);
        const float2 v1 =
            *reinterpret_cast<const float2*>(x + (size_t)s1 * DIN + 2 * lane);
        acc.x += v0.x + v1.x;
        acc.y += v0.y + v1.y;
    }
    if (j < end) {
        const int s0 = edge_src[j];
        const float2 v0 =
            *reinterpret_cast<const float2*>(x + (size_t)s0 * DIN + 2 * lane);
        acc.x += v0.x;
        acc.y += v0.y;
    }
    const float2 xv =
        *reinterpret_cast<const float2*>(x + (size_t)node * DIN + 2 * lane);
    float2 r;
    r.x = xv.x + acc.x;
    r.y = xv.y + acc.y;
    *reinterpret_cast<float2*>(xin + (size_t)node * DIN + 2 * lane) = r;
}

// ---------------------------------------------------------------------------
// Kernel 2: h1 = xin @ W1 + b1, plus BN1 sums. 16 rows/block, 16 accs/thread.
// 10000 = 625 * 16 exactly -> no bounds checks.
// ---------------------------------------------------------------------------
__global__ __launch_bounds__(256) void gemm1_k(
    const float* __restrict__ xin, const float* __restrict__ W1,
    const float* __restrict__ b1, float* __restrict__ h1,
    float* __restrict__ sum1, float* __restrict__ sq1) {
    __shared__ float xs[16][DIN];  // 8 KB
    const int row0 = blockIdx.x * 16;
    const int tid = threadIdx.x;

    {
        const float4* src =
            reinterpret_cast<const float4*>(xin + (size_t)row0 * DIN);
        float4* dst = reinterpret_cast<float4*>(&xs[0][0]);
#pragma unroll
        for (int i = 0; i < 2; ++i) dst[tid + 256 * i] = src[tid + 256 * i];
    }
    __syncthreads();

    const int j = tid;
    float acc[16];
    const float bj = b1[j];
#pragma unroll
    for (int r = 0; r < 16; ++r) acc[r] = bj;

    for (int k = 0; k < DIN; k += 4) {
        const float w0 = W1[(size_t)(k + 0) * DOUT + j];
        const float w1 = W1[(size_t)(k + 1) * DOUT + j];
        const float w2 = W1[(size_t)(k + 2) * DOUT + j];
        const float w3 = W1[(size_t)(k + 3) * DOUT + j];
#pragma unroll
        for (int r = 0; r < 16; ++r) {
            const float4 xv = *reinterpret_cast<const float4*>(&xs[r][k]);
            acc[r] = fmaf(xv.x, w0, acc[r]);
            acc[r] = fmaf(xv.y, w1, acc[r]);
            acc[r] = fmaf(xv.z, w2, acc[r]);
            acc[r] = fmaf(xv.w, w3, acc[r]);
        }
    }

    float s = 0.f, sq = 0.f;
#pragma unroll
    for (int r = 0; r < 16; ++r) {
        h1[(size_t)(row0 + r) * DOUT + j] = acc[r];
        s += acc[r];
        sq += acc[r] * acc[r];
    }
    atomicAdd(&sum1[j], s);
    atomicAdd(&sq1[j], sq);
}

// ---------------------------------------------------------------------------
// Kernel 3: BN finalize -> per-feature scale/shift
// ---------------------------------------------------------------------------
__global__ void bn_final_k(const float* __restrict__ sum,
                           const float* __restrict__ sq,
                           const float* __restrict__ gamma,
                           const float* __restrict__ beta,
                           float* __restrict__ scale,
                           float* __restrict__ shift) {
    const int j = threadIdx.x;  // 256
    const float nInv = 1.0f / (float)NN;
    const float mean = sum[j] * nInv;
    const float var = sq[j] * nInv - mean * mean;
    const float sc = gamma[j] * rsqrtf(var + BN_EPS);
    scale[j] = sc;
    shift[j] = beta[j] - mean * sc;
}

// ---------------------------------------------------------------------------
// Kernel 4: h2 = relu(bn1(h1)) @ W2 + b2, plus BN2 sums. 16 rows/block.
// ---------------------------------------------------------------------------
__global__ __launch_bounds__(256) void gemm2_k(
    const float* __restrict__ h1, const float* __restrict__ scale1,
    const float* __restrict__ shift1, const float* __restrict__ W2,
    const float* __restrict__ b2, float* __restrict__ h2,
    float* __restrict__ sum2, float* __restrict__ sq2) {
    __shared__ float gs[16][DOUT];  // 16 KB
    const int row0 = blockIdx.x * 16;
    const int tid = threadIdx.x;

    {
        const float4* s4 = reinterpret_cast<const float4*>(scale1);
        const float4* h4 = reinterpret_cast<const float4*>(shift1);
        const float4* src =
            reinterpret_cast<const float4*>(h1 + (size_t)row0 * DOUT);
        float4* dst = reinterpret_cast<float4*>(&gs[0][0]);
#pragma unroll
        for (int i = 0; i < 4; ++i) {
            const int u = tid + 256 * i;      // u in [0, 1024)
            const int k4 = u & 63;            // DOUT/4 = 64
            const float4 h = src[u];
            const float4 sc = s4[k4];
            const float4 sh = h4[k4];
            float4 g;
            g.x = fmaxf(fmaf(h.x, sc.x, sh.x), 0.f);
            g.y = fmaxf(fmaf(h.y, sc.y, sh.y), 0.f);
            g.z = fmaxf(fmaf(h.z, sc.z, sh.z), 0.f);
            g.w = fmaxf(fmaf(h.w, sc.w, sh.w), 0.f);
            dst[u] = g;
        }
    }
    __syncthreads();

    const int j = tid;
    float acc[16];
    const float bj = b2[j];
#pragma unroll
    for (int r = 0; r < 16; ++r) acc[r] = bj;

    for (int k = 0; k < DOUT; k += 4) {
        const float w0 = W2[(size_t)(k + 0) * DOUT + j];
        const float w1 = W2[(size_t)(k + 1) * DOUT + j];
        const float w2 = W2[(size_t)(k + 2) * DOUT + j];
        const float w3 = W2[(size_t)(k + 3) * DOUT + j];
#pragma unroll
        for (int r = 0; r < 16; ++r) {
            const float4 xv = *reinterpret_cast<const float4*>(&gs[r][k]);
            acc[r] = fmaf(xv.x, w0, acc[r]);
            acc[r] = fmaf(xv.y, w1, acc[r]);
            acc[r] = fmaf(xv.z, w2, acc[r]);
            acc[r] = fmaf(xv.w, w3, acc[r]);
        }
    }

    float s = 0.f, sq = 0.f;
#pragma unroll
    for (int r = 0; r < 16; ++r) {
        h2[(size_t)(row0 + r) * DOUT + j] = acc[r];
        s += acc[r];
        sq += acc[r] * acc[r];
    }
    atomicAdd(&sum2[j], s);
    atomicAdd(&sq2[j], sq);
}

// ---------------------------------------------------------------------------
// Kernel 5: out = relu(bn2(h2)), float4
// ---------------------------------------------------------------------------
__global__ __launch_bounds__(256) void bn_relu_out_k(
    const float* __restrict__ h2, const float* __restrict__ scale2,
    const float* __restrict__ shift2, float* __restrict__ out) {
    const int u = blockIdx.x * 256 + threadIdx.x;  // float4 index
    if (u < NN * DOUT / 4) {
        const int k4 = u & 63;
        const float4 h = reinterpret_cast<const float4*>(h2)[u];
        const float4 sc = reinterpret_cast<const float4*>(scale2)[k4];
        const float4 sh = reinterpret_cast<const float4*>(shift2)[k4];
        float4 g;
        g.x = fmaxf(fmaf(h.x, sc.x, sh.x), 0.f);
        g.y = fmaxf(fmaf(h.y, sc.y, sh.y), 0.f);
        g.z = fmaxf(fmaf(h.z, sc.z, sh.z), 0.f);
        g.w = fmaxf(fmaf(h.w, sc.w, sh.w), 0.f);
        reinterpret_cast<float4*>(out)[u] = g;
    }
}

// ---------------------------------------------------------------------------
extern "C" void kernel_launch(void* const* d_in, const int* in_sizes, int n_in,
                              void* d_out, int out_size, void* d_ws,
                              size_t ws_size, hipStream_t stream) {
    const float* x      = (const float*)d_in[0];
    const int*   ei     = (const int*)d_in[1];
    const float* W1     = (const float*)d_in[2];
    const float* b1     = (const float*)d_in[3];
    const float* gamma1 = (const float*)d_in[4];
    const float* beta1  = (const float*)d_in[5];
    const float* W2     = (const float*)d_in[6];
    const float* b2     = (const float*)d_in[7];
    const float* gamma2 = (const float*)d_in[8];
    const float* beta2  = (const float*)d_in[9];
    const int E = in_sizes[1] / 2;

    // ws layout (bytes):
    // [stats 8192][deg 40064][offsets 40064][cursor 40064][edge_src 4E]
    // [xin N*DIN*4][h1 N*DOUT*4][h2 N*DOUT*4]
    char* w = (char*)d_ws;
    float* stats   = (float*)w;
    float* sum1    = stats + 0;
    float* sq1     = stats + 256;
    float* scale1  = stats + 512;
    float* shift1  = stats + 768;
    float* sum2    = stats + 1024;
    float* sq2     = stats + 1280;
    float* scale2  = stats + 1536;
    float* shift2  = stats + 1792;
    int* deg       = (int*)(w + 8192);
    int* offsets   = (int*)(w + 8192 + 40064);
    int* cursor    = (int*)(w + 8192 + 2 * 40064);
    int* edge_src  = (int*)(w + 8192 + 3 * 40064);
    float* xin     = (float*)(w + 8192 + 3 * 40064 + (size_t)E * 4);
    float* h1      = xin + (size_t)NN * DIN;
    float* h2      = h1 + (size_t)NN * DOUT;
    float* out     = (float*)d_out;

    hipMemsetAsync(d_ws, 0, 8192 + 40064, stream);

    hist_k<<<80, 256, 0, stream>>>(ei, deg, E);
    scan_k<<<1, 1024, 0, stream>>>(deg, offsets, cursor);
    fill_k<<<2048, 256, 0, stream>>>(ei, cursor, edge_src, E);
    aggregate_k<<<(NN + 3) / 4, 256, 0, stream>>>(x, offsets, edge_src, xin);
    gemm1_k<<<NN / 16, 256, 0, stream>>>(xin, W1, b1, h1, sum1, sq1);
    bn_final_k<<<1, 256, 0, stream>>>(sum1, sq1, gamma1, beta1, scale1, shift1);
    gemm2_k<<<NN / 16, 256, 0, stream>>>(h1, scale1, shift1, W2, b2, h2,
                                         sum2, sq2);
    bn_final_k<<<1, 256, 0, stream>>>(sum2, sq2, gamma2, beta2, scale2, shift2);
    bn_relu_out_k<<<(NN * DOUT / 4 + 255) / 256, 256, 0, stream>>>(
        h2, scale2, shift2, out);
}